// Round 1
// baseline (577.717 us; speedup 1.0000x reference)
//
#include <hip/hip_runtime.h>

namespace {
constexpr int Bb = 8, Hh = 56, Ww = 56, Cc = 192;
constexpr int NQ  = Hh * Ww;        // 3136
constexpr int NKV = 28 * 28;        // 784
constexpr int NHEADS = 3;
constexpr float SCALE = 0.125f;     // 64^-0.5
constexpr float EPS = 1e-5f;
}

// ---------------------------------------------------------------------------
// depthwise 3x3 conv (SAME) + batchnorm (inference)
// ---------------------------------------------------------------------------
__global__ __launch_bounds__(256) void dwbn_kernel(
    const float* __restrict__ x, const float* __restrict__ w,
    const float* __restrict__ gamma, const float* __restrict__ beta,
    const float* __restrict__ mean, const float* __restrict__ var,
    float* __restrict__ out, int OH, int OW, int stride, int pad)
{
  int idx = blockIdx.x * 256 + threadIdx.x;
  int total = Bb * OH * OW * Cc;
  if (idx >= total) return;
  int c = idx % Cc;
  int t = idx / Cc;
  int ow = t % OW; t /= OW;
  int oh = t % OH; int b = t / OH;
  float acc = 0.f;
#pragma unroll
  for (int kh = 0; kh < 3; ++kh) {
    int ih = oh * stride - pad + kh;
    if (ih < 0 || ih >= Hh) continue;
#pragma unroll
    for (int kw = 0; kw < 3; ++kw) {
      int iw = ow * stride - pad + kw;
      if (iw < 0 || iw >= Ww) continue;
      acc += x[((size_t)(b * Hh + ih) * Ww + iw) * Cc + c] * w[(kh * 3 + kw) * Cc + c];
    }
  }
  float sc = gamma[c] / sqrtf(var[c] + EPS);
  out[idx] = (acc - mean[c]) * sc + beta[c];
}

// ---------------------------------------------------------------------------
// fp32 GEMM: C[M,N] = A[M,K] * Bw[K,N] (+ bias). M%64==0, N%64==0, K%32==0.
// 64x64 tile, 256 threads, 4x4 micro-tile.
// ---------------------------------------------------------------------------
__global__ __launch_bounds__(256) void gemm64_kernel(
    const float* __restrict__ A, const float* __restrict__ Bw,
    const float* __restrict__ bias, float* __restrict__ Cout,
    int M, int N, int K)
{
  __shared__ float As[64][36];   // [m][k], row 144B (16B aligned)
  __shared__ float Bs[32][68];   // [k][n], row 272B (16B aligned)

  const int nb = N / 64;
  const int bm = blockIdx.x / nb, bn = blockIdx.x % nb;
  const int row0 = bm * 64, col0 = bn * 64;
  const int tid = threadIdx.x;
  const int tx = tid & 15, ty = tid >> 4;

  float acc[4][4] = {};

  for (int k0 = 0; k0 < K; k0 += 32) {
    {
      const int m = tid >> 3, k4 = tid & 7;  // m 0..31, k4 0..7
      float4 a0 = *(const float4*)&A[(size_t)(row0 + m) * K + k0 + k4 * 4];
      float4 a1 = *(const float4*)&A[(size_t)(row0 + m + 32) * K + k0 + k4 * 4];
      *(float4*)&As[m][k4 * 4] = a0;
      *(float4*)&As[m + 32][k4 * 4] = a1;
    }
    {
      const int k = tid >> 4, n4 = tid & 15; // k 0..15, n4 0..15
      float4 b0 = *(const float4*)&Bw[(size_t)(k0 + k) * N + col0 + n4 * 4];
      float4 b1 = *(const float4*)&Bw[(size_t)(k0 + k + 16) * N + col0 + n4 * 4];
      *(float4*)&Bs[k][n4 * 4] = b0;
      *(float4*)&Bs[k + 16][n4 * 4] = b1;
    }
    __syncthreads();

#pragma unroll
    for (int k4 = 0; k4 < 8; ++k4) {
      float4 av[4], bv[4];
#pragma unroll
      for (int i = 0; i < 4; ++i) av[i] = *(const float4*)&As[ty * 4 + i][k4 * 4];
#pragma unroll
      for (int u = 0; u < 4; ++u) bv[u] = *(const float4*)&Bs[k4 * 4 + u][tx * 4];
#pragma unroll
      for (int u = 0; u < 4; ++u)
#pragma unroll
        for (int i = 0; i < 4; ++i) {
          float a = (&av[i].x)[u];
          acc[i][0] += a * bv[u].x;
          acc[i][1] += a * bv[u].y;
          acc[i][2] += a * bv[u].z;
          acc[i][3] += a * bv[u].w;
        }
    }
    __syncthreads();
  }

#pragma unroll
  for (int i = 0; i < 4; ++i) {
    const int r = row0 + ty * 4 + i;
#pragma unroll
    for (int j = 0; j < 4; ++j) {
      const int cidx = col0 + tx * 4 + j;
      float v = acc[i][j];
      if (bias) v += bias[cidx];
      Cout[(size_t)r * N + cidx] = v;
    }
  }
}

// ---------------------------------------------------------------------------
// flash attention: per block one (b, head, q-tile of 64 rows).
// q: [B, 3136, 192] (h*64+d), kv: [B, 784, 384] (k at h*64+d, v at 192+h*64+d)
// o: [B, 3136, 192]
// ---------------------------------------------------------------------------
__global__ __launch_bounds__(256) void attn_kernel(
    const float* __restrict__ q, const float* __restrict__ kv,
    float* __restrict__ o)
{
  __shared__ float Qs[64][68];   // [qrow][d]
  __shared__ float Ks[32][68];   // [kvrow][d]
  __shared__ float Vs[32][64];   // [kvrow][d]
  __shared__ float Ps[64][36];   // [qrow][kvcol]

  const int blk = blockIdx.x;
  const int qt = blk % 49;
  const int bh = blk / 49;
  const int h = bh % NHEADS;
  const int b = bh / NHEADS;
  const int n0 = qt * 64;
  const int tid = threadIdx.x;
  const int tx = tid & 15, ty = tid >> 4;

  // load Q tile [64][64]
  {
    const int r = tid >> 2;
    const int f0 = tid & 3;
    const float* qrow = q + ((size_t)(b * NQ + n0 + r) * 192) + h * 64;
#pragma unroll
    for (int u = 0; u < 4; ++u) {
      const int f = f0 + 4 * u;
      *(float4*)&Qs[r][f * 4] = *(const float4*)&qrow[f * 4];
    }
  }

  float m_reg[4], l_reg[4], oacc[4][4];
#pragma unroll
  for (int i = 0; i < 4; ++i) {
    m_reg[i] = -1e30f; l_reg[i] = 0.f;
#pragma unroll
    for (int j = 0; j < 4; ++j) oacc[i][j] = 0.f;
  }

  const int NT = (NKV + 31) / 32;  // 25 (last tile has 16 valid rows)
  for (int kt = 0; kt < NT; ++kt) {
    __syncthreads();
    // stage K/V tile rows kt*32..+31
    {
      const int r = tid >> 3;      // 0..31
      const int f0 = tid & 7;
      const int j = kt * 32 + r;
      const bool valid = (j < NKV);
      const float* base = kv + (size_t)(b * NKV + (valid ? j : 0)) * 384 + h * 64;
#pragma unroll
      for (int u = 0; u < 2; ++u) {
        const int f = f0 + 8 * u;
        float4 kvv = valid ? *(const float4*)&base[f * 4] : make_float4(0.f, 0.f, 0.f, 0.f);
        float4 vvv = valid ? *(const float4*)&base[192 + f * 4] : make_float4(0.f, 0.f, 0.f, 0.f);
        *(float4*)&Ks[r][f * 4] = kvv;
        *(float4*)&Vs[r][f * 4] = vvv;
      }
    }
    __syncthreads();

    // S = Q K^T (cols c = tx + 16*j)
    float s[4][2] = {{0.f, 0.f}, {0.f, 0.f}, {0.f, 0.f}, {0.f, 0.f}};
#pragma unroll
    for (int k4 = 0; k4 < 16; ++k4) {
      float4 bv0 = *(const float4*)&Ks[tx][k4 * 4];
      float4 bv1 = *(const float4*)&Ks[tx + 16][k4 * 4];
#pragma unroll
      for (int i = 0; i < 4; ++i) {
        float4 av = *(const float4*)&Qs[ty * 4 + i][k4 * 4];
        s[i][0] += av.x * bv0.x + av.y * bv0.y + av.z * bv0.z + av.w * bv0.w;
        s[i][1] += av.x * bv1.x + av.y * bv1.y + av.z * bv1.z + av.w * bv1.w;
      }
    }

    // online softmax, per-row state in registers (row group = 16 lanes)
    const int c0 = kt * 32 + tx, c1 = c0 + 16;
    float alpha[4];
#pragma unroll
    for (int i = 0; i < 4; ++i) {
      float s0 = (c0 < NKV) ? s[i][0] * SCALE : -1e30f;
      float s1 = (c1 < NKV) ? s[i][1] * SCALE : -1e30f;
      float tmax = fmaxf(s0, s1);
#pragma unroll
      for (int d = 1; d < 16; d <<= 1) tmax = fmaxf(tmax, __shfl_xor(tmax, d, 16));
      float mnew = fmaxf(m_reg[i], tmax);
      float p0 = __expf(s0 - mnew);
      float p1 = __expf(s1 - mnew);
      float psum = p0 + p1;
#pragma unroll
      for (int d = 1; d < 16; d <<= 1) psum += __shfl_xor(psum, d, 16);
      alpha[i] = __expf(m_reg[i] - mnew);
      l_reg[i] = l_reg[i] * alpha[i] + psum;
      m_reg[i] = mnew;
      Ps[ty * 4 + i][tx] = p0;
      Ps[ty * 4 + i][tx + 16] = p1;
    }
    __syncthreads();

    // O = O*alpha + P @ V
#pragma unroll
    for (int i = 0; i < 4; ++i)
#pragma unroll
      for (int j = 0; j < 4; ++j) oacc[i][j] *= alpha[i];

#pragma unroll
    for (int k4 = 0; k4 < 8; ++k4) {
      float4 pv[4];
#pragma unroll
      for (int i = 0; i < 4; ++i) pv[i] = *(const float4*)&Ps[ty * 4 + i][k4 * 4];
#pragma unroll
      for (int u = 0; u < 4; ++u) {
        float4 vv = *(const float4*)&Vs[k4 * 4 + u][tx * 4];
#pragma unroll
        for (int i = 0; i < 4; ++i) {
          float p = (&pv[i].x)[u];
          oacc[i][0] += p * vv.x;
          oacc[i][1] += p * vv.y;
          oacc[i][2] += p * vv.z;
          oacc[i][3] += p * vv.w;
        }
      }
    }
  }

  // epilogue: divide by softmax denom, store
#pragma unroll
  for (int i = 0; i < 4; ++i) {
    const int r = ty * 4 + i;
    const float inv = 1.0f / l_reg[i];
    float4 res;
    res.x = oacc[i][0] * inv;
    res.y = oacc[i][1] * inv;
    res.z = oacc[i][2] * inv;
    res.w = oacc[i][3] * inv;
    *(float4*)&o[(size_t)(b * NQ + n0 + r) * 192 + h * 64 + tx * 4] = res;
  }
}

// ---------------------------------------------------------------------------
extern "C" void kernel_launch(void* const* d_in, const int* in_sizes, int n_in,
                              void* d_out, int out_size, void* d_ws, size_t ws_size,
                              hipStream_t stream)
{
  const float* x        = (const float*)d_in[0];
  const float* dw_q     = (const float*)d_in[1];
  const float* q_gamma  = (const float*)d_in[2];
  const float* q_beta   = (const float*)d_in[3];
  const float* q_mean   = (const float*)d_in[4];
  const float* q_var    = (const float*)d_in[5];
  const float* pw_q     = (const float*)d_in[6];
  const float* dw_kv    = (const float*)d_in[7];
  const float* kv_gamma = (const float*)d_in[8];
  const float* kv_beta  = (const float*)d_in[9];
  const float* kv_mean  = (const float*)d_in[10];
  const float* kv_var   = (const float*)d_in[11];
  const float* pw_kv    = (const float*)d_in[12];
  const float* out_w    = (const float*)d_in[13];
  const float* out_b    = (const float*)d_in[14];
  float* out = (float*)d_out;

  float* bufA = (float*)d_ws;                       // 25088*192 (q_dw, later o)
  float* bufB = bufA + (size_t)25088 * 192;         // 25088*192 (q)
  float* bufC = bufB + (size_t)25088 * 192;         // 6272*384  (kv)

  // 1. depthwise+BN (q path, stride 1, pad 1) -> bufA
  dwbn_kernel<<<(25088 * 192 + 255) / 256, 256, 0, stream>>>(
      x, dw_q, q_gamma, q_beta, q_mean, q_var, bufA, 56, 56, 1, 1);
  // 2. pointwise q: bufA x pw_q -> bufB
  gemm64_kernel<<<392 * 3, 256, 0, stream>>>(bufA, pw_q, nullptr, bufB, 25088, 192, 192);
  // 3. depthwise+BN (kv path, stride 2, pad 0) -> bufA (q_dw dead)
  dwbn_kernel<<<(6272 * 192 + 255) / 256, 256, 0, stream>>>(
      x, dw_kv, kv_gamma, kv_beta, kv_mean, kv_var, bufA, 28, 28, 2, 0);
  // 4. pointwise kv: bufA x pw_kv -> bufC
  gemm64_kernel<<<98 * 6, 256, 0, stream>>>(bufA, pw_kv, nullptr, bufC, 6272, 384, 192);
  // 5. attention: (bufB, bufC) -> bufA (kv_dw dead)
  attn_kernel<<<8 * 3 * 49, 256, 0, stream>>>(bufB, bufC, bufA);
  // 6. output projection + bias -> d_out
  gemm64_kernel<<<392 * 3, 256, 0, stream>>>(bufA, out_w, out_b, out, 25088, 192, 192);
}

// Round 2
// 225.095 us; speedup vs baseline: 2.5666x; 2.5666x over previous
//
#include <hip/hip_runtime.h>

namespace {
constexpr int Bb = 8, Hh = 56, Ww = 56, Cc = 192;
constexpr int NQ  = Hh * Ww;        // 3136
constexpr int NKV = 28 * 28;        // 784
constexpr float SCALE = 0.125f;     // 64^-0.5
constexpr float EPS = 1e-5f;
}

typedef __attribute__((ext_vector_type(8))) short          bf16x8;
typedef __attribute__((ext_vector_type(4))) float          f32x4;
typedef __attribute__((ext_vector_type(8))) unsigned short u16x8;

__device__ inline unsigned short f2b(float f) {
  unsigned u = __builtin_bit_cast(unsigned, f);
  u += 0x7FFFu + ((u >> 16) & 1u);            // round-to-nearest-even
  return (unsigned short)(u >> 16);
}

__device__ inline uint2 pack4(float a, float b, float c, float d) {
  uint2 r;
  r.x = (unsigned)f2b(a) | ((unsigned)f2b(b) << 16);
  r.y = (unsigned)f2b(c) | ((unsigned)f2b(d) << 16);
  return r;
}

// ---------------------------------------------------------------------------
// depthwise 3x3 conv (SAME) + batchnorm (inference)
// ---------------------------------------------------------------------------
__global__ __launch_bounds__(256) void dwbn_kernel(
    const float* __restrict__ x, const float* __restrict__ w,
    const float* __restrict__ gamma, const float* __restrict__ beta,
    const float* __restrict__ mean, const float* __restrict__ var,
    float* __restrict__ out, int OH, int OW, int stride, int pad)
{
  int idx = blockIdx.x * 256 + threadIdx.x;
  int total = Bb * OH * OW * Cc;
  if (idx >= total) return;
  int c = idx % Cc;
  int t = idx / Cc;
  int ow = t % OW; t /= OW;
  int oh = t % OH; int b = t / OH;
  float acc = 0.f;
#pragma unroll
  for (int kh = 0; kh < 3; ++kh) {
    int ih = oh * stride - pad + kh;
    if (ih < 0 || ih >= Hh) continue;
#pragma unroll
    for (int kw = 0; kw < 3; ++kw) {
      int iw = ow * stride - pad + kw;
      if (iw < 0 || iw >= Ww) continue;
      acc += x[((size_t)(b * Hh + ih) * Ww + iw) * Cc + c] * w[(kh * 3 + kw) * Cc + c];
    }
  }
  float sc = gamma[c] / sqrtf(var[c] + EPS);
  out[idx] = (acc - mean[c]) * sc + beta[c];
}

// ---------------------------------------------------------------------------
// fp32 GEMM (out-proj): C[M,N] = A[M,K]*Bw[K,N] + bias
// ---------------------------------------------------------------------------
__global__ __launch_bounds__(256) void gemm64_kernel(
    const float* __restrict__ A, const float* __restrict__ Bw,
    const float* __restrict__ bias, float* __restrict__ Cout,
    int M, int N, int K)
{
  __shared__ float As[64][36];
  __shared__ float Bs[32][68];

  const int nb = N / 64;
  const int bm = blockIdx.x / nb, bn = blockIdx.x % nb;
  const int row0 = bm * 64, col0 = bn * 64;
  const int tid = threadIdx.x;
  const int tx = tid & 15, ty = tid >> 4;

  float acc[4][4] = {};

  for (int k0 = 0; k0 < K; k0 += 32) {
    {
      const int m = tid >> 3, k4 = tid & 7;
      float4 a0 = *(const float4*)&A[(size_t)(row0 + m) * K + k0 + k4 * 4];
      float4 a1 = *(const float4*)&A[(size_t)(row0 + m + 32) * K + k0 + k4 * 4];
      *(float4*)&As[m][k4 * 4] = a0;
      *(float4*)&As[m + 32][k4 * 4] = a1;
    }
    {
      const int k = tid >> 4, n4 = tid & 15;
      float4 b0 = *(const float4*)&Bw[(size_t)(k0 + k) * N + col0 + n4 * 4];
      float4 b1 = *(const float4*)&Bw[(size_t)(k0 + k + 16) * N + col0 + n4 * 4];
      *(float4*)&Bs[k][n4 * 4] = b0;
      *(float4*)&Bs[k + 16][n4 * 4] = b1;
    }
    __syncthreads();
#pragma unroll
    for (int k4 = 0; k4 < 8; ++k4) {
      float4 av[4], bv[4];
#pragma unroll
      for (int i = 0; i < 4; ++i) av[i] = *(const float4*)&As[ty * 4 + i][k4 * 4];
#pragma unroll
      for (int u = 0; u < 4; ++u) bv[u] = *(const float4*)&Bs[k4 * 4 + u][tx * 4];
#pragma unroll
      for (int u = 0; u < 4; ++u)
#pragma unroll
        for (int i = 0; i < 4; ++i) {
          float a = (&av[i].x)[u];
          acc[i][0] += a * bv[u].x;
          acc[i][1] += a * bv[u].y;
          acc[i][2] += a * bv[u].z;
          acc[i][3] += a * bv[u].w;
        }
    }
    __syncthreads();
  }

#pragma unroll
  for (int i = 0; i < 4; ++i) {
    const int r = row0 + ty * 4 + i;
#pragma unroll
    for (int j = 0; j < 4; ++j) {
      const int cidx = col0 + tx * 4 + j;
      float v = acc[i][j];
      if (bias) v += bias[cidx];
      Cout[(size_t)r * N + cidx] = v;
    }
  }
}

// ---------------------------------------------------------------------------
// fp32 GEMM mainloop, bf16 epilogue into attention-friendly layouts.
//   cols <  192: QK layout  dst[((b*3+h)*NR + row)*64 + d]        (NR=3136 or 784)
//   cols >= 192: V transposed dst[((b*3+h)*64 + d)*784 + row]
// ---------------------------------------------------------------------------
__global__ __launch_bounds__(256) void gemm_pw_bf16(
    const float* __restrict__ A, const float* __restrict__ Bw,
    unsigned short* __restrict__ QK, unsigned short* __restrict__ Vt,
    int M, int N, int K, int NR)
{
  __shared__ float As[64][36];
  __shared__ float Bs[32][68];

  const int nb = N / 64;
  const int bm = blockIdx.x / nb, bn = blockIdx.x % nb;
  const int row0 = bm * 64, col0 = bn * 64;
  const int tid = threadIdx.x;
  const int tx = tid & 15, ty = tid >> 4;

  float acc[4][4] = {};

  for (int k0 = 0; k0 < K; k0 += 32) {
    {
      const int m = tid >> 3, k4 = tid & 7;
      float4 a0 = *(const float4*)&A[(size_t)(row0 + m) * K + k0 + k4 * 4];
      float4 a1 = *(const float4*)&A[(size_t)(row0 + m + 32) * K + k0 + k4 * 4];
      *(float4*)&As[m][k4 * 4] = a0;
      *(float4*)&As[m + 32][k4 * 4] = a1;
    }
    {
      const int k = tid >> 4, n4 = tid & 15;
      float4 b0 = *(const float4*)&Bw[(size_t)(k0 + k) * N + col0 + n4 * 4];
      float4 b1 = *(const float4*)&Bw[(size_t)(k0 + k + 16) * N + col0 + n4 * 4];
      *(float4*)&Bs[k][n4 * 4] = b0;
      *(float4*)&Bs[k + 16][n4 * 4] = b1;
    }
    __syncthreads();
#pragma unroll
    for (int k4 = 0; k4 < 8; ++k4) {
      float4 av[4], bv[4];
#pragma unroll
      for (int i = 0; i < 4; ++i) av[i] = *(const float4*)&As[ty * 4 + i][k4 * 4];
#pragma unroll
      for (int u = 0; u < 4; ++u) bv[u] = *(const float4*)&Bs[k4 * 4 + u][tx * 4];
#pragma unroll
      for (int u = 0; u < 4; ++u)
#pragma unroll
        for (int i = 0; i < 4; ++i) {
          float a = (&av[i].x)[u];
          acc[i][0] += a * bv[u].x;
          acc[i][1] += a * bv[u].y;
          acc[i][2] += a * bv[u].z;
          acc[i][3] += a * bv[u].w;
        }
    }
    __syncthreads();
  }

  const int c0 = col0 + tx * 4;
  if (c0 < 192) {               // Q or K: row-major [bh][row][64] bf16
    const int h = c0 >> 6, d0 = c0 & 63;
#pragma unroll
    for (int i = 0; i < 4; ++i) {
      const int r = row0 + ty * 4 + i;
      const int b = r / NR, rr = r - b * NR;
      uint2 v = pack4(acc[i][0], acc[i][1], acc[i][2], acc[i][3]);
      *reinterpret_cast<uint2*>(&QK[(((size_t)b * 3 + h) * NR + rr) * 64 + d0]) = v;
    }
  } else {                      // V: transposed [bh][d][784] bf16
    const int h = (c0 - 192) >> 6, d0 = (c0 - 192) & 63;
    const int r0 = row0 + ty * 4;
    const int b = r0 / 784, rr = r0 - b * 784;   // 784%4==0: micro-tile never crosses b
#pragma unroll
    for (int j = 0; j < 4; ++j) {
      uint2 v = pack4(acc[0][j], acc[1][j], acc[2][j], acc[3][j]);
      *reinterpret_cast<uint2*>(&Vt[(((size_t)b * 3 + h) * 64 + d0 + j) * 784 + rr]) = v;
    }
  }
}

// ---------------------------------------------------------------------------
// MFMA flash attention. Block = (bh, q-tile of 64). 4 waves; wave w owns
// q rows [w*16, w*16+16). mfma_f32_16x16x32_bf16:
//   A: row=lane&15, k=(lane>>4)*8+j ; B: col=lane&15, k=(lane>>4)*8+j
//   D: col=lane&15, row=(lane>>4)*4+reg
// ---------------------------------------------------------------------------
__global__ __launch_bounds__(256) void attn_mfma_kernel(
    const unsigned short* __restrict__ Qb, const unsigned short* __restrict__ Kb,
    const unsigned short* __restrict__ Vtb, float* __restrict__ o)
{
  __shared__ unsigned short QPs[64][72];  // Q tile, reused as P tile (wave-private rows)
  __shared__ unsigned short Ks[64][72];
  __shared__ unsigned short Vts[64][72];  // V transposed: [d][kv]

  const int blk = blockIdx.x;
  const int qt = blk % 49;
  const int bh = blk / 49;                // b*3 + h
  const int n0 = qt * 64;
  const int tid = threadIdx.x;
  const int lane = tid & 63;
  const int w = tid >> 6;
  const int lr = lane & 15, lg = lane >> 4;

  // stage Q tile (64 x 64 bf16)
  {
    const int row = tid >> 2, cc = tid & 3;
    const unsigned short* qrow = Qb + ((size_t)bh * NQ + (n0 + row)) * 64;
#pragma unroll
    for (int u = 0; u < 2; ++u) {
      const int c8 = cc + 4 * u;
      *(u16x8*)&QPs[row][c8 * 8] = *(const u16x8*)&qrow[c8 * 8];
    }
  }
  __syncthreads();
  const bf16x8 aq0 = *(const bf16x8*)&QPs[w * 16 + lr][lg * 8];
  const bf16x8 aq1 = *(const bf16x8*)&QPs[w * 16 + lr][32 + lg * 8];

  float mreg[4], lreg[4];
  f32x4 oacc[4];
#pragma unroll
  for (int r = 0; r < 4; ++r) { mreg[r] = -1e30f; lreg[r] = 0.f; }
#pragma unroll
  for (int nb = 0; nb < 4; ++nb) oacc[nb] = (f32x4){0.f, 0.f, 0.f, 0.f};

  for (int kt = 0; kt < 13; ++kt) {
    __syncthreads();
    {
      const int row = tid >> 2, cc = tid & 3;
      // K rows kt*64..+63 (clamped; masked later)
      const int kvg = (kt * 64 + row < NKV) ? kt * 64 + row : NKV - 1;
      const unsigned short* krow = Kb + ((size_t)bh * NKV + kvg) * 64;
#pragma unroll
      for (int u = 0; u < 2; ++u) {
        const int c8 = cc + 4 * u;
        *(u16x8*)&Ks[row][c8 * 8] = *(const u16x8*)&krow[c8 * 8];
      }
      // Vt rows d=row, kv window kt*64..+63 (zero-fill OOB)
      const unsigned short* vrow = Vtb + ((size_t)bh * 64 + row) * NKV;
#pragma unroll
      for (int u = 0; u < 2; ++u) {
        const int c8 = cc + 4 * u;
        const int kv0 = kt * 64 + c8 * 8;
        u16x8 vv = {0, 0, 0, 0, 0, 0, 0, 0};
        if (kv0 < NKV) vv = *(const u16x8*)&vrow[kv0];
        *(u16x8*)&Vts[row][c8 * 8] = vv;
      }
    }
    __syncthreads();

    // S = Q K^T (wave's 16 rows x 64 kv cols)
    f32x4 s[4];
#pragma unroll
    for (int nb = 0; nb < 4; ++nb) {
      const bf16x8 bk0 = *(const bf16x8*)&Ks[nb * 16 + lr][lg * 8];
      const bf16x8 bk1 = *(const bf16x8*)&Ks[nb * 16 + lr][32 + lg * 8];
      f32x4 acc = (f32x4){0.f, 0.f, 0.f, 0.f};
      acc = __builtin_amdgcn_mfma_f32_16x16x32_bf16(aq0, bk0, acc, 0, 0, 0);
      acc = __builtin_amdgcn_mfma_f32_16x16x32_bf16(aq1, bk1, acc, 0, 0, 0);
      s[nb] = acc;
    }

    // online softmax; row q = w*16 + lg*4 + r lives in 16 lanes (lg fixed), reg r
#pragma unroll
    for (int r = 0; r < 4; ++r) {
      float sv[4];
      float rmax = -1e30f;
#pragma unroll
      for (int nb = 0; nb < 4; ++nb) {
        float x = s[nb][r] * SCALE;
        if (kt * 64 + nb * 16 + lr >= NKV) x = -1e30f;
        sv[nb] = x;
        rmax = fmaxf(rmax, x);
      }
#pragma unroll
      for (int d = 1; d < 16; d <<= 1) rmax = fmaxf(rmax, __shfl_xor(rmax, d, 16));
      const float mnew = fmaxf(mreg[r], rmax);
      const float alpha = __expf(mreg[r] - mnew);
      mreg[r] = mnew;
      float psum = 0.f;
#pragma unroll
      for (int nb = 0; nb < 4; ++nb) {
        const float p = __expf(sv[nb] - mnew);
        psum += p;
        QPs[w * 16 + lg * 4 + r][nb * 16 + lr] = f2b(p);
      }
#pragma unroll
      for (int d = 1; d < 16; d <<= 1) psum += __shfl_xor(psum, d, 16);
      lreg[r] = lreg[r] * alpha + psum;
#pragma unroll
      for (int nb = 0; nb < 4; ++nb) oacc[nb][r] *= alpha;
    }

    // O += P V   (P rows are wave-private: no barrier, DS ops in-order per wave)
    const bf16x8 pa0 = *(const bf16x8*)&QPs[w * 16 + lr][lg * 8];
    const bf16x8 pa1 = *(const bf16x8*)&QPs[w * 16 + lr][32 + lg * 8];
#pragma unroll
    for (int nb = 0; nb < 4; ++nb) {
      const bf16x8 vb0 = *(const bf16x8*)&Vts[nb * 16 + lr][lg * 8];
      const bf16x8 vb1 = *(const bf16x8*)&Vts[nb * 16 + lr][32 + lg * 8];
      oacc[nb] = __builtin_amdgcn_mfma_f32_16x16x32_bf16(pa0, vb0, oacc[nb], 0, 0, 0);
      oacc[nb] = __builtin_amdgcn_mfma_f32_16x16x32_bf16(pa1, vb1, oacc[nb], 0, 0, 0);
    }
  }

  // epilogue: O / l, store fp32 [b][3136][192]
  const int b = bh / 3, h = bh - b * 3;
#pragma unroll
  for (int r = 0; r < 4; ++r) {
    const float inv = 1.f / lreg[r];
    const int qg = n0 + w * 16 + lg * 4 + r;
    float* orow = o + ((size_t)b * NQ + qg) * 192 + h * 64 + lr;
#pragma unroll
    for (int nb = 0; nb < 4; ++nb) orow[nb * 16] = oacc[nb][r] * inv;
  }
}

// ---------------------------------------------------------------------------
extern "C" void kernel_launch(void* const* d_in, const int* in_sizes, int n_in,
                              void* d_out, int out_size, void* d_ws, size_t ws_size,
                              hipStream_t stream)
{
  const float* x        = (const float*)d_in[0];
  const float* dw_q     = (const float*)d_in[1];
  const float* q_gamma  = (const float*)d_in[2];
  const float* q_beta   = (const float*)d_in[3];
  const float* q_mean   = (const float*)d_in[4];
  const float* q_var    = (const float*)d_in[5];
  const float* pw_q     = (const float*)d_in[6];
  const float* dw_kv    = (const float*)d_in[7];
  const float* kv_gamma = (const float*)d_in[8];
  const float* kv_beta  = (const float*)d_in[9];
  const float* kv_mean  = (const float*)d_in[10];
  const float* kv_var   = (const float*)d_in[11];
  const float* pw_kv    = (const float*)d_in[12];
  const float* out_w    = (const float*)d_in[13];
  const float* out_b    = (const float*)d_in[14];
  float* out = (float*)d_out;

  float* bufA = (float*)d_ws;                                    // 25088*192 f32
  unsigned short* Qbuf  = (unsigned short*)(bufA + (size_t)25088 * 192);  // 24*3136*64 bf16
  unsigned short* Kbuf  = Qbuf + (size_t)24 * 3136 * 64;         // 24*784*64 bf16
  unsigned short* Vtbuf = Kbuf + (size_t)24 * 784 * 64;          // 24*64*784 bf16

  // 1. depthwise+BN (q, stride 1, pad 1) -> bufA
  dwbn_kernel<<<(25088 * 192 + 255) / 256, 256, 0, stream>>>(
      x, dw_q, q_gamma, q_beta, q_mean, q_var, bufA, 56, 56, 1, 1);
  // 2. pointwise q -> Qbuf (bf16, per-head layout)
  gemm_pw_bf16<<<392 * 3, 256, 0, stream>>>(bufA, pw_q, Qbuf, nullptr, 25088, 192, 192, 3136);
  // 3. depthwise+BN (kv, stride 2, pad 0) -> bufA
  dwbn_kernel<<<(6272 * 192 + 255) / 256, 256, 0, stream>>>(
      x, dw_kv, kv_gamma, kv_beta, kv_mean, kv_var, bufA, 28, 28, 2, 0);
  // 4. pointwise kv -> Kbuf (row-major) + Vtbuf (transposed)
  gemm_pw_bf16<<<98 * 6, 256, 0, stream>>>(bufA, pw_kv, Kbuf, Vtbuf, 6272, 384, 192, 784);
  // 5. MFMA attention -> bufA (fp32 O)
  attn_mfma_kernel<<<8 * 3 * 49, 256, 0, stream>>>(Qbuf, Kbuf, Vtbuf, bufA);
  // 6. output projection + bias -> d_out
  gemm64_kernel<<<392 * 3, 256, 0, stream>>>(bufA, out_w, out_b, out, 25088, 192, 192);
}

// Round 3
// 139.771 us; speedup vs baseline: 4.1333x; 1.6105x over previous
//
#include <hip/hip_runtime.h>

namespace {
constexpr int Bb = 8, Hh = 56, Ww = 56, Cc = 192;
constexpr int NQ  = Hh * Ww;        // 3136
constexpr int NKV = 28 * 28;        // 784
constexpr float SCALE = 0.125f;     // 64^-0.5
constexpr float EPS = 1e-5f;
}

typedef __attribute__((ext_vector_type(8))) short          bf16x8;
typedef __attribute__((ext_vector_type(4))) float          f32x4;
typedef __attribute__((ext_vector_type(8))) unsigned short u16x8;

__device__ inline unsigned short f2b(float f) {
  unsigned u = __builtin_bit_cast(unsigned, f);
  u += 0x7FFFu + ((u >> 16) & 1u);            // round-to-nearest-even
  return (unsigned short)(u >> 16);
}

__device__ inline uint2 pack4(float a, float b, float c, float d) {
  uint2 r;
  r.x = (unsigned)f2b(a) | ((unsigned)f2b(b) << 16);
  r.y = (unsigned)f2b(c) | ((unsigned)f2b(d) << 16);
  return r;
}

// ---------------------------------------------------------------------------
// weight prep: fp32 [K][N] -> bf16 transposed [N][K]   (K=192 for all three)
// ---------------------------------------------------------------------------
__global__ __launch_bounds__(256) void prep_w_kernel(
    const float* __restrict__ pwq, const float* __restrict__ pwkv,
    const float* __restrict__ outw,
    unsigned short* __restrict__ wq, unsigned short* __restrict__ wkv,
    unsigned short* __restrict__ wo)
{
  int i = blockIdx.x * 256 + threadIdx.x;
  if (i < 36864) {                       // wq [192][192]
    int n = i / 192, k = i - n * 192;
    wq[i] = f2b(pwq[k * 192 + n]);
  } else if (i < 110592) {               // wkv [384][192]
    int j = i - 36864;
    int n = j / 192, k = j - n * 192;
    wkv[j] = f2b(pwkv[k * 384 + n]);
  } else if (i < 147456) {               // wo [192][192]
    int j = i - 110592;
    int n = j / 192, k = j - n * 192;
    wo[j] = f2b(outw[k * 192 + n]);
  }
}

// ---------------------------------------------------------------------------
// depthwise 3x3 conv (SAME) + batchnorm -> bf16 output [M][192]
// one thread = 4 channels (float4 loads, uint2 bf16 store)
// ---------------------------------------------------------------------------
__global__ __launch_bounds__(256) void dwbn_bf16_kernel(
    const float* __restrict__ x, const float* __restrict__ w,
    const float* __restrict__ gamma, const float* __restrict__ beta,
    const float* __restrict__ mean, const float* __restrict__ var,
    unsigned short* __restrict__ out, int OH, int OW, int stride, int pad)
{
  int idx = blockIdx.x * 256 + threadIdx.x;
  int total = Bb * OH * OW * 48;
  if (idx >= total) return;
  int c4 = idx % 48;
  int t = idx / 48;
  int ow = t % OW; t /= OW;
  int oh = t % OH; int b = t / OH;
  const int c = c4 * 4;

  float4 acc = make_float4(0.f, 0.f, 0.f, 0.f);
#pragma unroll
  for (int kh = 0; kh < 3; ++kh) {
    int ih = oh * stride - pad + kh;
    if (ih < 0 || ih >= Hh) continue;
#pragma unroll
    for (int kw = 0; kw < 3; ++kw) {
      int iw = ow * stride - pad + kw;
      if (iw < 0 || iw >= Ww) continue;
      float4 xv = *(const float4*)&x[((size_t)(b * Hh + ih) * Ww + iw) * Cc + c];
      float4 wv = *(const float4*)&w[(kh * 3 + kw) * Cc + c];
      acc.x += xv.x * wv.x; acc.y += xv.y * wv.y;
      acc.z += xv.z * wv.z; acc.w += xv.w * wv.w;
    }
  }
  float4 gm = *(const float4*)&gamma[c];
  float4 bt = *(const float4*)&beta[c];
  float4 mn = *(const float4*)&mean[c];
  float4 vr = *(const float4*)&var[c];
  float r0 = (acc.x - mn.x) * gm.x / sqrtf(vr.x + EPS) + bt.x;
  float r1 = (acc.y - mn.y) * gm.y / sqrtf(vr.y + EPS) + bt.y;
  float r2 = (acc.z - mn.z) * gm.z / sqrtf(vr.z + EPS) + bt.z;
  float r3 = (acc.w - mn.w) * gm.w / sqrtf(vr.w + EPS) + bt.w;
  const size_t row = (size_t)(b * OH + oh) * OW + ow;
  *reinterpret_cast<uint2*>(&out[row * 192 + c]) = pack4(r0, r1, r2, r3);
}

// ---------------------------------------------------------------------------
// bf16 MFMA GEMM: C[M,N] = A[M,192] * Bt[N,192]^T
// 128x64 tile, 256 threads (4 waves 2Mx2N), wave-tile 64x32, 16x16x32 MFMA.
// MODE 0: write Q/K layout  dst[((b*3+h)*NR + n)*64 + d], split M by NR
// MODE 1: cols<192 -> K layout (NR=784); cols>=192 -> Vt[(bh*64+d)*784+n]
// MODE 2: fp32 out[r*192+c] + bias
// ---------------------------------------------------------------------------
template <int MODE>
__global__ __launch_bounds__(256) void gemm_mfma(
    const unsigned short* __restrict__ A, const unsigned short* __restrict__ Bt,
    const float* __restrict__ bias, unsigned short* __restrict__ QK,
    unsigned short* __restrict__ Vt, float* __restrict__ O32,
    int N, int NR)
{
  __shared__ unsigned short As[128][72];
  __shared__ unsigned short Bs[64][72];

  const int nbl = N >> 6;
  const int bm = blockIdx.x / nbl, bn = blockIdx.x % nbl;
  const int row0 = bm << 7, col0 = bn << 6;
  const int tid = threadIdx.x;
  const int lane = tid & 63, w = tid >> 6;
  const int lr = lane & 15, lg = lane >> 4;
  const int wm = w >> 1, wn = w & 1;

  f32x4 acc[4][2];
#pragma unroll
  for (int mr = 0; mr < 4; ++mr)
#pragma unroll
    for (int nr = 0; nr < 2; ++nr) acc[mr][nr] = (f32x4){0.f, 0.f, 0.f, 0.f};

  for (int k0 = 0; k0 < 192; k0 += 64) {
    {
      const int r = tid >> 1, c0 = (tid & 1) * 32;
      const unsigned short* src = A + (size_t)(row0 + r) * 192 + k0 + c0;
#pragma unroll
      for (int u = 0; u < 4; ++u)
        *(u16x8*)&As[r][c0 + u * 8] = *(const u16x8*)&src[u * 8];
    }
    {
      const int n = tid >> 2, c0 = (tid & 3) * 16;
      const unsigned short* src = Bt + (size_t)(col0 + n) * 192 + k0 + c0;
#pragma unroll
      for (int u = 0; u < 2; ++u)
        *(u16x8*)&Bs[n][c0 + u * 8] = *(const u16x8*)&src[u * 8];
    }
    __syncthreads();
#pragma unroll
    for (int ks = 0; ks < 2; ++ks) {
      bf16x8 a[4], b[2];
#pragma unroll
      for (int mr = 0; mr < 4; ++mr)
        a[mr] = *(const bf16x8*)&As[wm * 64 + mr * 16 + lr][ks * 32 + lg * 8];
#pragma unroll
      for (int nr = 0; nr < 2; ++nr)
        b[nr] = *(const bf16x8*)&Bs[wn * 32 + nr * 16 + lr][ks * 32 + lg * 8];
#pragma unroll
      for (int mr = 0; mr < 4; ++mr)
#pragma unroll
        for (int nr = 0; nr < 2; ++nr)
          acc[mr][nr] = __builtin_amdgcn_mfma_f32_16x16x32_bf16(a[mr], b[nr], acc[mr][nr], 0, 0, 0);
    }
    __syncthreads();
  }

  // epilogue: D layout col = lr, row = lg*4 + j
#pragma unroll
  for (int mr = 0; mr < 4; ++mr) {
#pragma unroll
    for (int nr = 0; nr < 2; ++nr) {
      const int c = col0 + wn * 32 + nr * 16 + lr;
      const int rbase = row0 + wm * 64 + mr * 16 + lg * 4;
      if (MODE == 2) {
        const float bb = bias[c];
#pragma unroll
        for (int j = 0; j < 4; ++j)
          O32[(size_t)(rbase + j) * 192 + c] = acc[mr][nr][j] + bb;
      } else if (MODE == 0 || (MODE == 1 && c < 192)) {
        const int h = c >> 6, d = c & 63;
        const int b = rbase / NR;          // NR%4==0: 4-row group stays in one b
        const int n0 = rbase - b * NR;
#pragma unroll
        for (int j = 0; j < 4; ++j)
          QK[(((size_t)b * 3 + h) * NR + n0 + j) * 64 + d] = f2b(acc[mr][nr][j]);
      } else {                              // MODE 1, V columns -> transposed
        const int h = (c - 192) >> 6, d = (c - 192) & 63;
        const int b = rbase / 784;
        const int n0 = rbase - b * 784;
        uint2 v = pack4(acc[mr][nr][0], acc[mr][nr][1], acc[mr][nr][2], acc[mr][nr][3]);
        *reinterpret_cast<uint2*>(&Vt[(((size_t)b * 3 + h) * 64 + d) * 784 + n0]) = v;
      }
    }
  }
}

// ---------------------------------------------------------------------------
// MFMA flash attention (unchanged structure; output now bf16 [25088][192]).
// ---------------------------------------------------------------------------
__global__ __launch_bounds__(256) void attn_mfma_kernel(
    const unsigned short* __restrict__ Qb, const unsigned short* __restrict__ Kb,
    const unsigned short* __restrict__ Vtb, unsigned short* __restrict__ Ob)
{
  __shared__ unsigned short QPs[64][72];  // Q tile, reused as P tile (wave-private rows)
  __shared__ unsigned short Ks[64][72];
  __shared__ unsigned short Vts[64][72];  // V transposed: [d][kv]

  const int blk = blockIdx.x;
  const int qt = blk % 49;
  const int bh = blk / 49;                // b*3 + h
  const int n0 = qt * 64;
  const int tid = threadIdx.x;
  const int lane = tid & 63;
  const int w = tid >> 6;
  const int lr = lane & 15, lg = lane >> 4;

  {
    const int row = tid >> 2, cc = tid & 3;
    const unsigned short* qrow = Qb + ((size_t)bh * NQ + (n0 + row)) * 64;
#pragma unroll
    for (int u = 0; u < 2; ++u) {
      const int c8 = cc + 4 * u;
      *(u16x8*)&QPs[row][c8 * 8] = *(const u16x8*)&qrow[c8 * 8];
    }
  }
  __syncthreads();
  const bf16x8 aq0 = *(const bf16x8*)&QPs[w * 16 + lr][lg * 8];
  const bf16x8 aq1 = *(const bf16x8*)&QPs[w * 16 + lr][32 + lg * 8];

  float mreg[4], lreg[4];
  f32x4 oacc[4];
#pragma unroll
  for (int r = 0; r < 4; ++r) { mreg[r] = -1e30f; lreg[r] = 0.f; }
#pragma unroll
  for (int nb = 0; nb < 4; ++nb) oacc[nb] = (f32x4){0.f, 0.f, 0.f, 0.f};

  for (int kt = 0; kt < 13; ++kt) {
    __syncthreads();
    {
      const int row = tid >> 2, cc = tid & 3;
      const int kvg = (kt * 64 + row < NKV) ? kt * 64 + row : NKV - 1;
      const unsigned short* krow = Kb + ((size_t)bh * NKV + kvg) * 64;
#pragma unroll
      for (int u = 0; u < 2; ++u) {
        const int c8 = cc + 4 * u;
        *(u16x8*)&Ks[row][c8 * 8] = *(const u16x8*)&krow[c8 * 8];
      }
      const unsigned short* vrow = Vtb + ((size_t)bh * 64 + row) * NKV;
#pragma unroll
      for (int u = 0; u < 2; ++u) {
        const int c8 = cc + 4 * u;
        const int kv0 = kt * 64 + c8 * 8;
        u16x8 vv = {0, 0, 0, 0, 0, 0, 0, 0};
        if (kv0 < NKV) vv = *(const u16x8*)&vrow[kv0];
        *(u16x8*)&Vts[row][c8 * 8] = vv;
      }
    }
    __syncthreads();

    f32x4 s[4];
#pragma unroll
    for (int nb = 0; nb < 4; ++nb) {
      const bf16x8 bk0 = *(const bf16x8*)&Ks[nb * 16 + lr][lg * 8];
      const bf16x8 bk1 = *(const bf16x8*)&Ks[nb * 16 + lr][32 + lg * 8];
      f32x4 a = (f32x4){0.f, 0.f, 0.f, 0.f};
      a = __builtin_amdgcn_mfma_f32_16x16x32_bf16(aq0, bk0, a, 0, 0, 0);
      a = __builtin_amdgcn_mfma_f32_16x16x32_bf16(aq1, bk1, a, 0, 0, 0);
      s[nb] = a;
    }

#pragma unroll
    for (int r = 0; r < 4; ++r) {
      float sv[4];
      float rmax = -1e30f;
#pragma unroll
      for (int nb = 0; nb < 4; ++nb) {
        float xv = s[nb][r] * SCALE;
        if (kt * 64 + nb * 16 + lr >= NKV) xv = -1e30f;
        sv[nb] = xv;
        rmax = fmaxf(rmax, xv);
      }
#pragma unroll
      for (int d = 1; d < 16; d <<= 1) rmax = fmaxf(rmax, __shfl_xor(rmax, d, 16));
      const float mnew = fmaxf(mreg[r], rmax);
      const float alpha = __expf(mreg[r] - mnew);
      mreg[r] = mnew;
      float psum = 0.f;
#pragma unroll
      for (int nb = 0; nb < 4; ++nb) {
        const float p = __expf(sv[nb] - mnew);
        psum += p;
        QPs[w * 16 + lg * 4 + r][nb * 16 + lr] = f2b(p);
      }
#pragma unroll
      for (int d = 1; d < 16; d <<= 1) psum += __shfl_xor(psum, d, 16);
      lreg[r] = lreg[r] * alpha + psum;
#pragma unroll
      for (int nb = 0; nb < 4; ++nb) oacc[nb][r] *= alpha;
    }

    const bf16x8 pa0 = *(const bf16x8*)&QPs[w * 16 + lr][lg * 8];
    const bf16x8 pa1 = *(const bf16x8*)&QPs[w * 16 + lr][32 + lg * 8];
#pragma unroll
    for (int nb = 0; nb < 4; ++nb) {
      const bf16x8 vb0 = *(const bf16x8*)&Vts[nb * 16 + lr][lg * 8];
      const bf16x8 vb1 = *(const bf16x8*)&Vts[nb * 16 + lr][32 + lg * 8];
      oacc[nb] = __builtin_amdgcn_mfma_f32_16x16x32_bf16(pa0, vb0, oacc[nb], 0, 0, 0);
      oacc[nb] = __builtin_amdgcn_mfma_f32_16x16x32_bf16(pa1, vb1, oacc[nb], 0, 0, 0);
    }
  }

  const int b = bh / 3, h = bh - b * 3;
#pragma unroll
  for (int r = 0; r < 4; ++r) {
    const float inv = 1.f / lreg[r];
    const int qg = n0 + w * 16 + lg * 4 + r;
    unsigned short* orow = Ob + ((size_t)b * NQ + qg) * 192 + h * 64 + lr;
#pragma unroll
    for (int nb = 0; nb < 4; ++nb) orow[nb * 16] = f2b(oacc[nb][r] * inv);
  }
}

// ---------------------------------------------------------------------------
extern "C" void kernel_launch(void* const* d_in, const int* in_sizes, int n_in,
                              void* d_out, int out_size, void* d_ws, size_t ws_size,
                              hipStream_t stream)
{
  const float* x        = (const float*)d_in[0];
  const float* dw_q     = (const float*)d_in[1];
  const float* q_gamma  = (const float*)d_in[2];
  const float* q_beta   = (const float*)d_in[3];
  const float* q_mean   = (const float*)d_in[4];
  const float* q_var    = (const float*)d_in[5];
  const float* pw_q     = (const float*)d_in[6];
  const float* dw_kv    = (const float*)d_in[7];
  const float* kv_gamma = (const float*)d_in[8];
  const float* kv_beta  = (const float*)d_in[9];
  const float* kv_mean  = (const float*)d_in[10];
  const float* kv_var   = (const float*)d_in[11];
  const float* pw_kv    = (const float*)d_in[12];
  const float* out_w    = (const float*)d_in[13];
  const float* out_b    = (const float*)d_in[14];
  float* out = (float*)d_out;

  unsigned short* dwbuf = (unsigned short*)d_ws;          // 25088*192 (dw out, later O)
  unsigned short* Qbuf  = dwbuf + (size_t)25088 * 192;    // 24*3136*64
  unsigned short* Kbuf  = Qbuf + (size_t)24 * 3136 * 64;  // 24*784*64
  unsigned short* Vtbuf = Kbuf + (size_t)24 * 784 * 64;   // 24*64*784
  unsigned short* Wq    = Vtbuf + (size_t)24 * 784 * 64;  // 192*192
  unsigned short* Wkv   = Wq + 36864;                     // 384*192
  unsigned short* Wo    = Wkv + 73728;                    // 192*192

  // 0. weight transpose + bf16
  prep_w_kernel<<<576, 256, 0, stream>>>(pw_q, pw_kv, out_w, Wq, Wkv, Wo);
  // 1. depthwise+BN (q, stride 1, pad 1) -> dwbuf bf16
  dwbn_bf16_kernel<<<(25088 * 48 + 255) / 256, 256, 0, stream>>>(
      x, dw_q, q_gamma, q_beta, q_mean, q_var, dwbuf, 56, 56, 1, 1);
  // 2. pointwise q -> Qbuf (per-head layout)
  gemm_mfma<0><<<196 * 3, 256, 0, stream>>>(dwbuf, Wq, nullptr, Qbuf, nullptr, nullptr, 192, 3136);
  // 3. depthwise+BN (kv, stride 2, pad 0) -> dwbuf bf16
  dwbn_bf16_kernel<<<(6272 * 48 + 255) / 256, 256, 0, stream>>>(
      x, dw_kv, kv_gamma, kv_beta, kv_mean, kv_var, dwbuf, 28, 28, 2, 0);
  // 4. pointwise kv -> Kbuf + Vtbuf
  gemm_mfma<1><<<49 * 6, 256, 0, stream>>>(dwbuf, Wkv, nullptr, Kbuf, Vtbuf, nullptr, 384, 784);
  // 5. MFMA attention -> dwbuf (bf16 O, [25088][192])
  attn_mfma_kernel<<<8 * 3 * 49, 256, 0, stream>>>(Qbuf, Kbuf, Vtbuf, dwbuf);
  // 6. output projection + bias -> d_out (fp32)
  gemm_mfma<2><<<196 * 3, 256, 0, stream>>>(dwbuf, Wo, out_b, nullptr, nullptr, out, 192, 25088);
}

// Round 5
// 109.355 us; speedup vs baseline: 5.2829x; 1.2781x over previous
//
#include <hip/hip_runtime.h>

namespace {
constexpr int Bb = 8, Hh = 56, Ww = 56, Cc = 192;
constexpr int NQ  = Hh * Ww;        // 3136
constexpr int NKV = 28 * 28;        // 784
constexpr float EPS = 1e-5f;
}

typedef __attribute__((ext_vector_type(8))) short          bf16x8;
typedef __attribute__((ext_vector_type(4))) float          f32x4;
typedef __attribute__((ext_vector_type(8))) unsigned short u16x8;

__device__ inline unsigned short f2b(float f) {
  unsigned u = __builtin_bit_cast(unsigned, f);
  u += 0x7FFFu + ((u >> 16) & 1u);            // round-to-nearest-even
  return (unsigned short)(u >> 16);
}

__device__ inline uint2 pack4(float a, float b, float c, float d) {
  uint2 r;
  r.x = (unsigned)f2b(a) | ((unsigned)f2b(b) << 16);
  r.y = (unsigned)f2b(c) | ((unsigned)f2b(d) << 16);
  return r;
}

// ---------------------------------------------------------------------------
// weight prep: fp32 [K][N] -> bf16 transposed [N][K]   (K=192 for all three)
// ---------------------------------------------------------------------------
__global__ __launch_bounds__(256) void prep_w_kernel(
    const float* __restrict__ pwq, const float* __restrict__ pwkv,
    const float* __restrict__ outw,
    unsigned short* __restrict__ wq, unsigned short* __restrict__ wkv,
    unsigned short* __restrict__ wo)
{
  int i = blockIdx.x * 256 + threadIdx.x;
  if (i < 36864) {                       // wq [192][192]
    int n = i / 192, k = i - n * 192;
    wq[i] = f2b(pwq[k * 192 + n]);
  } else if (i < 110592) {               // wkv [384][192]
    int j = i - 36864;
    int n = j / 192, k = j - n * 192;
    wkv[j] = f2b(pwkv[k * 384 + n]);
  } else if (i < 147456) {               // wo [192][192]
    int j = i - 110592;
    int n = j / 192, k = j - n * 192;
    wo[j] = f2b(outw[k * 192 + n]);
  }
}

// ---------------------------------------------------------------------------
// depthwise 3x3 conv (SAME) + batchnorm -> bf16 output [M][192]
// ---------------------------------------------------------------------------
__global__ __launch_bounds__(256) void dwbn_bf16_kernel(
    const float* __restrict__ x, const float* __restrict__ w,
    const float* __restrict__ gamma, const float* __restrict__ beta,
    const float* __restrict__ mean, const float* __restrict__ var,
    unsigned short* __restrict__ out, int OH, int OW, int stride, int pad)
{
  int idx = blockIdx.x * 256 + threadIdx.x;
  int total = Bb * OH * OW * 48;
  if (idx >= total) return;
  int c4 = idx % 48;
  int t = idx / 48;
  int ow = t % OW; t /= OW;
  int oh = t % OH; int b = t / OH;
  const int c = c4 * 4;

  float4 acc = make_float4(0.f, 0.f, 0.f, 0.f);
#pragma unroll
  for (int kh = 0; kh < 3; ++kh) {
    int ih = oh * stride - pad + kh;
    if (ih < 0 || ih >= Hh) continue;
#pragma unroll
    for (int kw = 0; kw < 3; ++kw) {
      int iw = ow * stride - pad + kw;
      if (iw < 0 || iw >= Ww) continue;
      float4 xv = *(const float4*)&x[((size_t)(b * Hh + ih) * Ww + iw) * Cc + c];
      float4 wv = *(const float4*)&w[(kh * 3 + kw) * Cc + c];
      acc.x += xv.x * wv.x; acc.y += xv.y * wv.y;
      acc.z += xv.z * wv.z; acc.w += xv.w * wv.w;
    }
  }
  float4 gm = *(const float4*)&gamma[c];
  float4 bt = *(const float4*)&beta[c];
  float4 mn = *(const float4*)&mean[c];
  float4 vr = *(const float4*)&var[c];
  float r0 = (acc.x - mn.x) * gm.x / sqrtf(vr.x + EPS) + bt.x;
  float r1 = (acc.y - mn.y) * gm.y / sqrtf(vr.y + EPS) + bt.y;
  float r2 = (acc.z - mn.z) * gm.z / sqrtf(vr.z + EPS) + bt.z;
  float r3 = (acc.w - mn.w) * gm.w / sqrtf(vr.w + EPS) + bt.w;
  const size_t row = (size_t)(b * OH + oh) * OW + ow;
  *reinterpret_cast<uint2*>(&out[row * 192 + c]) = pack4(r0, r1, r2, r3);
}

// ---------------------------------------------------------------------------
// bf16 MFMA GEMM: C[M,N] = A[M,192] * Bt[N,192]^T
// MODE 0: Q layout (scaled by 0.125)  MODE 1: K layout + V transposed
// MODE 2: fp32 out + bias
// ---------------------------------------------------------------------------
template <int MODE>
__global__ __launch_bounds__(256) void gemm_mfma(
    const unsigned short* __restrict__ A, const unsigned short* __restrict__ Bt,
    const float* __restrict__ bias, unsigned short* __restrict__ QK,
    unsigned short* __restrict__ Vt, float* __restrict__ O32,
    int N, int NR)
{
  __shared__ unsigned short As[128][72];
  __shared__ unsigned short Bs[64][72];

  const int nbl = N >> 6;
  const int bm = blockIdx.x / nbl, bn = blockIdx.x % nbl;
  const int row0 = bm << 7, col0 = bn << 6;
  const int tid = threadIdx.x;
  const int lane = tid & 63, w = tid >> 6;
  const int lr = lane & 15, lg = lane >> 4;
  const int wm = w >> 1, wn = w & 1;

  f32x4 acc[4][2];
#pragma unroll
  for (int mr = 0; mr < 4; ++mr)
#pragma unroll
    for (int nr = 0; nr < 2; ++nr) acc[mr][nr] = (f32x4){0.f, 0.f, 0.f, 0.f};

  for (int k0 = 0; k0 < 192; k0 += 64) {
    {
      const int r = tid >> 1, c0 = (tid & 1) * 32;
      const unsigned short* src = A + (size_t)(row0 + r) * 192 + k0 + c0;
#pragma unroll
      for (int u = 0; u < 4; ++u)
        *(u16x8*)&As[r][c0 + u * 8] = *(const u16x8*)&src[u * 8];
    }
    {
      const int n = tid >> 2, c0 = (tid & 3) * 16;
      const unsigned short* src = Bt + (size_t)(col0 + n) * 192 + k0 + c0;
#pragma unroll
      for (int u = 0; u < 2; ++u)
        *(u16x8*)&Bs[n][c0 + u * 8] = *(const u16x8*)&src[u * 8];
    }
    __syncthreads();
#pragma unroll
    for (int ks = 0; ks < 2; ++ks) {
      bf16x8 a[4], b[2];
#pragma unroll
      for (int mr = 0; mr < 4; ++mr)
        a[mr] = *(const bf16x8*)&As[wm * 64 + mr * 16 + lr][ks * 32 + lg * 8];
#pragma unroll
      for (int nr = 0; nr < 2; ++nr)
        b[nr] = *(const bf16x8*)&Bs[wn * 32 + nr * 16 + lr][ks * 32 + lg * 8];
#pragma unroll
      for (int mr = 0; mr < 4; ++mr)
#pragma unroll
        for (int nr = 0; nr < 2; ++nr)
          acc[mr][nr] = __builtin_amdgcn_mfma_f32_16x16x32_bf16(a[mr], b[nr], acc[mr][nr], 0, 0, 0);
    }
    __syncthreads();
  }

#pragma unroll
  for (int mr = 0; mr < 4; ++mr) {
#pragma unroll
    for (int nr = 0; nr < 2; ++nr) {
      const int c = col0 + wn * 32 + nr * 16 + lr;
      const int rbase = row0 + wm * 64 + mr * 16 + lg * 4;
      if (MODE == 2) {
        const float bb = bias[c];
#pragma unroll
        for (int j = 0; j < 4; ++j)
          O32[(size_t)(rbase + j) * 192 + c] = acc[mr][nr][j] + bb;
      } else if (MODE == 0 || (MODE == 1 && c < 192)) {
        const int h = c >> 6, d = c & 63;
        const int b = rbase / NR;
        const int n0 = rbase - b * NR;
        const float sc = (MODE == 0) ? 0.125f : 1.0f;   // fold attn SCALE into Q (exact pow2)
#pragma unroll
        for (int j = 0; j < 4; ++j)
          QK[(((size_t)b * 3 + h) * NR + n0 + j) * 64 + d] = f2b(acc[mr][nr][j] * sc);
      } else {
        const int h = (c - 192) >> 6, d = (c - 192) & 63;
        const int b = rbase / 784;
        const int n0 = rbase - b * 784;
        uint2 v = pack4(acc[mr][nr][0], acc[mr][nr][1], acc[mr][nr][2], acc[mr][nr][3]);
        *reinterpret_cast<uint2*>(&Vt[(((size_t)b * 3 + h) * 64 + d) * 784 + n0]) = v;
      }
    }
  }
}

// ---------------------------------------------------------------------------
// MFMA flash attention, swapped-QK^T / no-max / deferred-denominator.
// Block = (bh, 64 q-rows); 4 waves, wave w owns q rows [w*16, w*16+16).
// S^T = mfma(K_frag, Q_frag): lane(lg,lr) holds S[q=lr][kv=kt*64+nb*16+lg*4+r]
// p = exp(s) (scores pre-scaled in Q; |s|<~0.6 so no overflow, math-identical
// to max-sub softmax). P -> LDS via 4x ds_write_b64 (wave-private rows),
// PV via the round-3-proven 16x16x32 path. No inline asm, no prefetch pipe.
// ---------------------------------------------------------------------------
__global__ __launch_bounds__(256) void attn_mfma_kernel(
    const unsigned short* __restrict__ Qb, const unsigned short* __restrict__ Kb,
    const unsigned short* __restrict__ Vtb, unsigned short* __restrict__ Ob)
{
  __shared__ unsigned short Ks[64][72];
  __shared__ unsigned short Vts[64][72];   // V transposed tile: [d][kv_local]
  __shared__ unsigned short Ps[64][66];    // P tile: [q][kv_local], wave-private rows
  __shared__ float ls[4][16];

  const int blk = blockIdx.x;
  const int qt = blk % 49;
  const int bh = blk / 49;                // b*3 + h
  const int n0 = qt * 64;
  const int tid = threadIdx.x;
  const int lane = tid & 63;
  const int w = tid >> 6;
  const int lr = lane & 15, lg = lane >> 4;
  const int row = tid >> 2, cc = tid & 3; // staging coords (4 threads/row)

  // Q fragment straight from global (one strided read per lane, L2-resident)
  const unsigned short* qrow = Qb + ((size_t)bh * NQ + n0 + w * 16 + lr) * 64;
  const bf16x8 aq0 = *(const bf16x8*)&qrow[lg * 8];
  const bf16x8 aq1 = *(const bf16x8*)&qrow[32 + lg * 8];

  const unsigned short* kbase = Kb + (size_t)bh * NKV * 64;
  const unsigned short* vrow  = Vtb + ((size_t)bh * 64 + row) * NKV;

  f32x4 oacc[4];
#pragma unroll
  for (int db = 0; db < 4; ++db) oacc[db] = (f32x4){0.f, 0.f, 0.f, 0.f};
  float lsum = 0.f;

  for (int kt = 0; kt < 13; ++kt) {
    __syncthreads();                       // previous tile fully consumed
    {
      // K rows kt*64..+63 (clamped; masked via P later)
      const int kvg = (kt * 64 + row < NKV) ? kt * 64 + row : NKV - 1;
      const unsigned short* kp = kbase + (size_t)kvg * 64;
      *(u16x8*)&Ks[row][cc * 8]      = *(const u16x8*)&kp[cc * 8];
      *(u16x8*)&Ks[row][cc * 8 + 32] = *(const u16x8*)&kp[cc * 8 + 32];
      // Vt rows d=row, kv window kt*64..+63 (zero-fill OOB chunks; 784%8==0)
#pragma unroll
      for (int u = 0; u < 2; ++u) {
        const int c8 = cc + 4 * u;
        const int kv0 = kt * 64 + c8 * 8;
        u16x8 vv = {0, 0, 0, 0, 0, 0, 0, 0};
        if (kv0 < NKV) vv = *(const u16x8*)&vrow[kv0];
        *(u16x8*)&Vts[row][c8 * 8] = vv;
      }
    }
    __syncthreads();

    // S^T = K.Q^T : st[nb][r] = S[q=lr][kv = kt*64 + nb*16 + lg*4 + r]
    f32x4 st[4];
#pragma unroll
    for (int nb = 0; nb < 4; ++nb) {
      const bf16x8 bk0 = *(const bf16x8*)&Ks[nb * 16 + lr][lg * 8];
      const bf16x8 bk1 = *(const bf16x8*)&Ks[nb * 16 + lr][32 + lg * 8];
      f32x4 a = (f32x4){0.f, 0.f, 0.f, 0.f};
      a = __builtin_amdgcn_mfma_f32_16x16x32_bf16(bk0, aq0, a, 0, 0, 0);
      a = __builtin_amdgcn_mfma_f32_16x16x32_bf16(bk1, aq1, a, 0, 0, 0);
      st[nb] = a;
    }

    // p = exp(s), mask tail, partial denominator, pack -> Ps (b64 writes)
    const int kvb = kt * 64 + lg * 4;
#pragma unroll
    for (int nb = 0; nb < 4; ++nb) {
      float p[4];
#pragma unroll
      for (int r = 0; r < 4; ++r)
        p[r] = (kvb + nb * 16 + r < NKV) ? __expf(st[nb][r]) : 0.f;
      lsum += (p[0] + p[1]) + (p[2] + p[3]);
      uint2 u = pack4(p[0], p[1], p[2], p[3]);
      *reinterpret_cast<uint2*>(&Ps[w * 16 + lr][nb * 16 + lg * 4]) = u;
    }

    // O += P V  (Ps rows wave-private: same-wave DS in-order, no barrier)
    const bf16x8 pa0 = *(const bf16x8*)&Ps[w * 16 + lr][lg * 8];
    const bf16x8 pa1 = *(const bf16x8*)&Ps[w * 16 + lr][32 + lg * 8];
#pragma unroll
    for (int db = 0; db < 4; ++db) {
      const bf16x8 vb0 = *(const bf16x8*)&Vts[db * 16 + lr][lg * 8];
      const bf16x8 vb1 = *(const bf16x8*)&Vts[db * 16 + lr][32 + lg * 8];
      oacc[db] = __builtin_amdgcn_mfma_f32_16x16x32_bf16(pa0, vb0, oacc[db], 0, 0, 0);
      oacc[db] = __builtin_amdgcn_mfma_f32_16x16x32_bf16(pa1, vb1, oacc[db], 0, 0, 0);
    }
  }

  // final denominator: lanes {lr, lr+16, lr+32, lr+48} hold partials for q=lr
  float l = lsum;
  l += __shfl_xor(l, 16);
  l += __shfl_xor(l, 32);
  if (lg == 0) ls[w][lr] = l;
  const float4 lv = *(const float4*)&ls[w][lg * 4];   // wave-private, in-order

  const int b = bh / 3, h = bh - b * 3;
  float linv[4];
#pragma unroll
  for (int j = 0; j < 4; ++j) linv[j] = 1.f / ((&lv.x)[j]);
#pragma unroll
  for (int j = 0; j < 4; ++j) {
    const int qg = n0 + w * 16 + lg * 4 + j;   // oacc row = q
    unsigned short* orow = Ob + ((size_t)b * NQ + qg) * 192 + h * 64 + lr;
#pragma unroll
    for (int db = 0; db < 4; ++db) orow[db * 16] = f2b(oacc[db][j] * linv[j]);
  }
}

// ---------------------------------------------------------------------------
extern "C" void kernel_launch(void* const* d_in, const int* in_sizes, int n_in,
                              void* d_out, int out_size, void* d_ws, size_t ws_size,
                              hipStream_t stream)
{
  const float* x        = (const float*)d_in[0];
  const float* dw_q     = (const float*)d_in[1];
  const float* q_gamma  = (const float*)d_in[2];
  const float* q_beta   = (const float*)d_in[3];
  const float* q_mean   = (const float*)d_in[4];
  const float* q_var    = (const float*)d_in[5];
  const float* pw_q     = (const float*)d_in[6];
  const float* dw_kv    = (const float*)d_in[7];
  const float* kv_gamma = (const float*)d_in[8];
  const float* kv_beta  = (const float*)d_in[9];
  const float* kv_mean  = (const float*)d_in[10];
  const float* kv_var   = (const float*)d_in[11];
  const float* pw_kv    = (const float*)d_in[12];
  const float* out_w    = (const float*)d_in[13];
  const float* out_b    = (const float*)d_in[14];
  float* out = (float*)d_out;

  unsigned short* dwbuf = (unsigned short*)d_ws;          // 25088*192 (dw out, later O)
  unsigned short* Qbuf  = dwbuf + (size_t)25088 * 192;    // 24*3136*64
  unsigned short* Kbuf  = Qbuf + (size_t)24 * 3136 * 64;  // 24*784*64
  unsigned short* Vtbuf = Kbuf + (size_t)24 * 784 * 64;   // 24*64*784
  unsigned short* Wq    = Vtbuf + (size_t)24 * 784 * 64;  // 192*192
  unsigned short* Wkv   = Wq + 36864;                     // 384*192
  unsigned short* Wo    = Wkv + 73728;                    // 192*192

  // 0. weight transpose + bf16
  prep_w_kernel<<<576, 256, 0, stream>>>(pw_q, pw_kv, out_w, Wq, Wkv, Wo);
  // 1. depthwise+BN (q, stride 1, pad 1) -> dwbuf bf16
  dwbn_bf16_kernel<<<(25088 * 48 + 255) / 256, 256, 0, stream>>>(
      x, dw_q, q_gamma, q_beta, q_mean, q_var, dwbuf, 56, 56, 1, 1);
  // 2. pointwise q -> Qbuf (per-head layout, pre-scaled by 0.125)
  gemm_mfma<0><<<196 * 3, 256, 0, stream>>>(dwbuf, Wq, nullptr, Qbuf, nullptr, nullptr, 192, 3136);
  // 3. depthwise+BN (kv, stride 2, pad 0) -> dwbuf bf16
  dwbn_bf16_kernel<<<(6272 * 48 + 255) / 256, 256, 0, stream>>>(
      x, dw_kv, kv_gamma, kv_beta, kv_mean, kv_var, dwbuf, 28, 28, 2, 0);
  // 4. pointwise kv -> Kbuf + Vtbuf
  gemm_mfma<1><<<49 * 6, 256, 0, stream>>>(dwbuf, Wkv, nullptr, Kbuf, Vtbuf, nullptr, 384, 784);
  // 5. MFMA attention -> dwbuf (bf16 O, [25088][192])
  attn_mfma_kernel<<<8 * 3 * 49, 256, 0, stream>>>(Qbuf, Kbuf, Vtbuf, dwbuf);
  // 6. output projection + bias -> d_out (fp32)
  gemm_mfma<2><<<196 * 3, 256, 0, stream>>>(dwbuf, Wo, out_b, nullptr, nullptr, out, 192, 25088);
}

// Round 6
// 89.004 us; speedup vs baseline: 6.4909x; 1.2286x over previous
//
#include <hip/hip_runtime.h>
#include <hip/hip_bf16.h>

namespace {
constexpr int Bb = 8, Hh = 56, Ww = 56, Cc = 192;
constexpr int NQ  = Hh * Ww;        // 3136
constexpr int NKV = 28 * 28;        // 784
constexpr float EPS = 1e-5f;
constexpr float QSCALE = 0.125f * 1.4426950408889634f;  // head scale * log2(e)
}

typedef __attribute__((ext_vector_type(8))) short          bf16x8;
typedef __attribute__((ext_vector_type(4))) float          f32x4;
typedef __attribute__((ext_vector_type(8))) unsigned short u16x8;

__device__ inline unsigned short f2b(float f) {
  __hip_bfloat16 h = __float2bfloat16(f);     // RNE, hardware cvt path
  return __builtin_bit_cast(unsigned short, h);
}

__device__ inline uint2 pack4(float a, float b, float c, float d) {
  uint2 r;
  r.x = (unsigned)f2b(a) | ((unsigned)f2b(b) << 16);
  r.y = (unsigned)f2b(c) | ((unsigned)f2b(d) << 16);
  return r;
}

// ---------------------------------------------------------------------------
// depthwise 3x3 conv (SAME) + batchnorm body (4 channels / thread)
// ---------------------------------------------------------------------------
__device__ inline void dwbn_body(
    int idx, const float* __restrict__ x, const float* __restrict__ w,
    const float* __restrict__ gamma, const float* __restrict__ beta,
    const float* __restrict__ mean, const float* __restrict__ var,
    unsigned short* __restrict__ out, int OH, int OW, int stride, int pad)
{
  int c4 = idx % 48;
  int t = idx / 48;
  int ow = t % OW; t /= OW;
  int oh = t % OH; int b = t / OH;
  const int c = c4 * 4;

  float4 acc = make_float4(0.f, 0.f, 0.f, 0.f);
#pragma unroll
  for (int kh = 0; kh < 3; ++kh) {
    int ih = oh * stride - pad + kh;
    if (ih < 0 || ih >= Hh) continue;
#pragma unroll
    for (int kw = 0; kw < 3; ++kw) {
      int iw = ow * stride - pad + kw;
      if (iw < 0 || iw >= Ww) continue;
      float4 xv = *(const float4*)&x[((size_t)(b * Hh + ih) * Ww + iw) * Cc + c];
      float4 wv = *(const float4*)&w[(kh * 3 + kw) * Cc + c];
      acc.x += xv.x * wv.x; acc.y += xv.y * wv.y;
      acc.z += xv.z * wv.z; acc.w += xv.w * wv.w;
    }
  }
  float4 gm = *(const float4*)&gamma[c];
  float4 bt = *(const float4*)&beta[c];
  float4 mn = *(const float4*)&mean[c];
  float4 vr = *(const float4*)&var[c];
  float r0 = (acc.x - mn.x) * gm.x / sqrtf(vr.x + EPS) + bt.x;
  float r1 = (acc.y - mn.y) * gm.y / sqrtf(vr.y + EPS) + bt.y;
  float r2 = (acc.z - mn.z) * gm.z / sqrtf(vr.z + EPS) + bt.z;
  float r3 = (acc.w - mn.w) * gm.w / sqrtf(vr.w + EPS) + bt.w;
  const size_t row = (size_t)(b * OH + oh) * OW + ow;
  *reinterpret_cast<uint2*>(&out[row * 192 + c]) = pack4(r0, r1, r2, r3);
}

// ---------------------------------------------------------------------------
// fused stage 1: dwbn(q) [blocks 0..4703] + dwbn(kv) [4704..5879]
//              + weight transpose->bf16 [5880..6455]
// ---------------------------------------------------------------------------
__global__ __launch_bounds__(256) void stage1_kernel(
    const float* __restrict__ x,
    const float* __restrict__ dw_q, const float* __restrict__ q_gamma,
    const float* __restrict__ q_beta, const float* __restrict__ q_mean,
    const float* __restrict__ q_var,
    const float* __restrict__ dw_kv, const float* __restrict__ kv_gamma,
    const float* __restrict__ kv_beta, const float* __restrict__ kv_mean,
    const float* __restrict__ kv_var,
    const float* __restrict__ pwq, const float* __restrict__ pwkv,
    const float* __restrict__ outw,
    unsigned short* __restrict__ dwq, unsigned short* __restrict__ dwkv,
    unsigned short* __restrict__ wq, unsigned short* __restrict__ wkv,
    unsigned short* __restrict__ wo)
{
  const int blk = blockIdx.x;
  if (blk < 4704) {
    dwbn_body(blk * 256 + threadIdx.x, x, dw_q, q_gamma, q_beta, q_mean, q_var,
              dwq, 56, 56, 1, 1);
  } else if (blk < 5880) {
    dwbn_body((blk - 4704) * 256 + threadIdx.x, x, dw_kv, kv_gamma, kv_beta,
              kv_mean, kv_var, dwkv, 28, 28, 2, 0);
  } else {
    int i = (blk - 5880) * 256 + threadIdx.x;
    if (i < 36864) {                       // wq [192][192]
      int n = i / 192, k = i - n * 192;
      wq[i] = f2b(pwq[k * 192 + n]);
    } else if (i < 110592) {               // wkv [384][192]
      int j = i - 36864;
      int n = j / 192, k = j - n * 192;
      wkv[j] = f2b(pwkv[k * 384 + n]);
    } else {                               // wo [192][192]
      int j = i - 110592;
      int n = j / 192, k = j - n * 192;
      wo[j] = f2b(outw[k * 192 + n]);
    }
  }
}

// ---------------------------------------------------------------------------
// fused bf16 MFMA GEMM for q & kv pointwise:
//  blocks [0,588): dwq[25088,192] x Wq^T -> Qbuf (per-head, scaled by QSCALE)
//  blocks [588,882): dwkv[6272,192] x Wkv^T -> Kbuf (per-head) + Vtbuf (transposed)
// ---------------------------------------------------------------------------
__global__ __launch_bounds__(256) void gemm_qkv_kernel(
    const unsigned short* __restrict__ dwq, const unsigned short* __restrict__ dwkv,
    const unsigned short* __restrict__ Wq, const unsigned short* __restrict__ Wkv,
    unsigned short* __restrict__ Qbuf, unsigned short* __restrict__ Kbuf,
    unsigned short* __restrict__ Vtbuf)
{
  __shared__ unsigned short As[128][72];
  __shared__ unsigned short Bs[64][72];

  const int blk = blockIdx.x;
  const bool isQ = blk < 588;
  const int lb = isQ ? blk : blk - 588;
  const unsigned short* __restrict__ A  = isQ ? dwq : dwkv;
  const unsigned short* __restrict__ Bt = isQ ? Wq : Wkv;
  const int nbl = isQ ? 3 : 6;
  const int NR  = isQ ? 3136 : 784;

  const int bm = lb / nbl, bn = lb % nbl;
  const int row0 = bm << 7, col0 = bn << 6;
  const int tid = threadIdx.x;
  const int lane = tid & 63, w = tid >> 6;
  const int lr = lane & 15, lg = lane >> 4;
  const int wm = w >> 1, wn = w & 1;

  f32x4 acc[4][2];
#pragma unroll
  for (int mr = 0; mr < 4; ++mr)
#pragma unroll
    for (int nr = 0; nr < 2; ++nr) acc[mr][nr] = (f32x4){0.f, 0.f, 0.f, 0.f};

  for (int k0 = 0; k0 < 192; k0 += 64) {
    {
      const int r = tid >> 1, c0 = (tid & 1) * 32;
      const unsigned short* src = A + (size_t)(row0 + r) * 192 + k0 + c0;
#pragma unroll
      for (int u = 0; u < 4; ++u)
        *(u16x8*)&As[r][c0 + u * 8] = *(const u16x8*)&src[u * 8];
    }
    {
      const int n = tid >> 2, c0 = (tid & 3) * 16;
      const unsigned short* src = Bt + (size_t)(col0 + n) * 192 + k0 + c0;
#pragma unroll
      for (int u = 0; u < 2; ++u)
        *(u16x8*)&Bs[n][c0 + u * 8] = *(const u16x8*)&src[u * 8];
    }
    __syncthreads();
#pragma unroll
    for (int ks = 0; ks < 2; ++ks) {
      bf16x8 a[4], b[2];
#pragma unroll
      for (int mr = 0; mr < 4; ++mr)
        a[mr] = *(const bf16x8*)&As[wm * 64 + mr * 16 + lr][ks * 32 + lg * 8];
#pragma unroll
      for (int nr = 0; nr < 2; ++nr)
        b[nr] = *(const bf16x8*)&Bs[wn * 32 + nr * 16 + lr][ks * 32 + lg * 8];
#pragma unroll
      for (int mr = 0; mr < 4; ++mr)
#pragma unroll
        for (int nr = 0; nr < 2; ++nr)
          acc[mr][nr] = __builtin_amdgcn_mfma_f32_16x16x32_bf16(a[mr], b[nr], acc[mr][nr], 0, 0, 0);
    }
    __syncthreads();
  }

#pragma unroll
  for (int mr = 0; mr < 4; ++mr) {
#pragma unroll
    for (int nr = 0; nr < 2; ++nr) {
      const int c = col0 + wn * 32 + nr * 16 + lr;
      const int rbase = row0 + wm * 64 + mr * 16 + lg * 4;
      if (isQ) {
        const int h = c >> 6, d = c & 63;
        const int b = rbase / 3136;
        const int n0 = rbase - b * 3136;
#pragma unroll
        for (int j = 0; j < 4; ++j)
          Qbuf[(((size_t)b * 3 + h) * 3136 + n0 + j) * 64 + d] = f2b(acc[mr][nr][j] * QSCALE);
      } else if (c < 192) {
        const int h = c >> 6, d = c & 63;
        const int b = rbase / 784;
        const int n0 = rbase - b * 784;
#pragma unroll
        for (int j = 0; j < 4; ++j)
          Kbuf[(((size_t)b * 3 + h) * 784 + n0 + j) * 64 + d] = f2b(acc[mr][nr][j]);
      } else {
        const int h = (c - 192) >> 6, d = (c - 192) & 63;
        const int b = rbase / 784;
        const int n0 = rbase - b * 784;
        uint2 v = pack4(acc[mr][nr][0], acc[mr][nr][1], acc[mr][nr][2], acc[mr][nr][3]);
        *reinterpret_cast<uint2*>(&Vtbuf[(((size_t)b * 3 + h) * 64 + d) * 784 + n0]) = v;
      }
    }
  }
}

// ---------------------------------------------------------------------------
// output projection: O[25088,192](bf16) x Wo^T + bias -> fp32
// ---------------------------------------------------------------------------
__global__ __launch_bounds__(256) void gemm_out_kernel(
    const unsigned short* __restrict__ A, const unsigned short* __restrict__ Bt,
    const float* __restrict__ bias, float* __restrict__ O32)
{
  __shared__ unsigned short As[128][72];
  __shared__ unsigned short Bs[64][72];

  const int bm = blockIdx.x / 3, bn = blockIdx.x % 3;
  const int row0 = bm << 7, col0 = bn << 6;
  const int tid = threadIdx.x;
  const int lane = tid & 63, w = tid >> 6;
  const int lr = lane & 15, lg = lane >> 4;
  const int wm = w >> 1, wn = w & 1;

  f32x4 acc[4][2];
#pragma unroll
  for (int mr = 0; mr < 4; ++mr)
#pragma unroll
    for (int nr = 0; nr < 2; ++nr) acc[mr][nr] = (f32x4){0.f, 0.f, 0.f, 0.f};

  for (int k0 = 0; k0 < 192; k0 += 64) {
    {
      const int r = tid >> 1, c0 = (tid & 1) * 32;
      const unsigned short* src = A + (size_t)(row0 + r) * 192 + k0 + c0;
#pragma unroll
      for (int u = 0; u < 4; ++u)
        *(u16x8*)&As[r][c0 + u * 8] = *(const u16x8*)&src[u * 8];
    }
    {
      const int n = tid >> 2, c0 = (tid & 3) * 16;
      const unsigned short* src = Bt + (size_t)(col0 + n) * 192 + k0 + c0;
#pragma unroll
      for (int u = 0; u < 2; ++u)
        *(u16x8*)&Bs[n][c0 + u * 8] = *(const u16x8*)&src[u * 8];
    }
    __syncthreads();
#pragma unroll
    for (int ks = 0; ks < 2; ++ks) {
      bf16x8 a[4], b[2];
#pragma unroll
      for (int mr = 0; mr < 4; ++mr)
        a[mr] = *(const bf16x8*)&As[wm * 64 + mr * 16 + lr][ks * 32 + lg * 8];
#pragma unroll
      for (int nr = 0; nr < 2; ++nr)
        b[nr] = *(const bf16x8*)&Bs[wn * 32 + nr * 16 + lr][ks * 32 + lg * 8];
#pragma unroll
      for (int mr = 0; mr < 4; ++mr)
#pragma unroll
        for (int nr = 0; nr < 2; ++nr)
          acc[mr][nr] = __builtin_amdgcn_mfma_f32_16x16x32_bf16(a[mr], b[nr], acc[mr][nr], 0, 0, 0);
    }
    __syncthreads();
  }

#pragma unroll
  for (int mr = 0; mr < 4; ++mr) {
#pragma unroll
    for (int nr = 0; nr < 2; ++nr) {
      const int c = col0 + wn * 32 + nr * 16 + lr;
      const int rbase = row0 + wm * 64 + mr * 16 + lg * 4;
      const float bb = bias[c];
#pragma unroll
      for (int j = 0; j < 4; ++j)
        O32[(size_t)(rbase + j) * 192 + c] = acc[mr][nr][j] + bb;
    }
  }
}

// ---------------------------------------------------------------------------
// MFMA flash attention: swapped-QK^T, no-max softmax (exp2, scale pre-folded),
// deferred denominator, reg-prefetch pipeline (T14), conflict-tuned LDS.
// Block = (bh, 64 q-rows); 4 waves; wave w owns q rows [w*16, w*16+16).
// Staging map: row = w*16+(lane&15), chunk = lane>>4  (2-way banks on write).
// Tiles 0..11 unmasked; tail tile 12 has only nb=0 valid (compile-time mask).
// ---------------------------------------------------------------------------
__global__ __launch_bounds__(256) void attn_mfma_kernel(
    const unsigned short* __restrict__ Qb, const unsigned short* __restrict__ Kb,
    const unsigned short* __restrict__ Vtb, unsigned short* __restrict__ Ob)
{
  __shared__ unsigned short Ks[64][72];
  __shared__ unsigned short Vts[64][72];   // V transposed tile: [d][kv_local]
  __shared__ unsigned short Ps[64][72];    // P tile (wave-private rows), 72-pad
  __shared__ float ls[4][16];

  const int blk = blockIdx.x;
  const int qt = blk % 49;
  const int bh = blk / 49;                 // b*3 + h
  const int n0 = qt * 64;
  const int tid = threadIdx.x;
  const int lane = tid & 63;
  const int w = tid >> 6;
  const int lr = lane & 15, lg = lane >> 4;
  const int srow = w * 16 + lr;            // staging row
  const int scc  = lg;                     // staging chunk

  // Q fragment straight from global (L2-resident)
  const unsigned short* qrow = Qb + ((size_t)bh * NQ + n0 + w * 16 + lr) * 64;
  const bf16x8 aq0 = *(const bf16x8*)&qrow[lg * 8];
  const bf16x8 aq1 = *(const bf16x8*)&qrow[32 + lg * 8];

  const unsigned short* kbase = Kb + (size_t)bh * NKV * 64;
  const unsigned short* vrow  = Vtb + ((size_t)bh * 64 + srow) * NKV;

  // stage tile 0
  u16x8 kr0, kr1, vr0, vr1;
  {
    const unsigned short* kp = kbase + (size_t)srow * 64;
    kr0 = *(const u16x8*)&kp[scc * 8];
    kr1 = *(const u16x8*)&kp[scc * 8 + 32];
    vr0 = *(const u16x8*)&vrow[scc * 8];
    vr1 = *(const u16x8*)&vrow[scc * 8 + 32];
  }
  *(u16x8*)&Ks[srow][scc * 8]       = kr0;
  *(u16x8*)&Ks[srow][scc * 8 + 32]  = kr1;
  *(u16x8*)&Vts[srow][scc * 8]      = vr0;
  *(u16x8*)&Vts[srow][scc * 8 + 32] = vr1;
  __syncthreads();

  f32x4 oacc[4];
#pragma unroll
  for (int db = 0; db < 4; ++db) oacc[db] = (f32x4){0.f, 0.f, 0.f, 0.f};
  float lsum = 0.f;

  for (int kt = 0; kt < 12; ++kt) {
    // prefetch tile kt+1 into regs (latency hides under compute)
    {
      const int nk = kt + 1;
      const int kvg = (nk * 64 + srow < NKV) ? nk * 64 + srow : NKV - 1;
      const unsigned short* kp = kbase + (size_t)kvg * 64;
      kr0 = *(const u16x8*)&kp[scc * 8];
      kr1 = *(const u16x8*)&kp[scc * 8 + 32];
      const int vb = nk * 64 + scc * 8;
      const int vc0 = (vb      <= NKV - 8) ? vb      : NKV - 8;
      const int vc1 = (vb + 32 <= NKV - 8) ? vb + 32 : NKV - 8;
      vr0 = *(const u16x8*)&vrow[vc0];
      vr1 = *(const u16x8*)&vrow[vc1];
    }

    // S^T = K.Q^T : st[nb][r] = S[q=lr][kv = kt*64 + nb*16 + lg*4 + r]
    f32x4 st[4];
#pragma unroll
    for (int nb = 0; nb < 4; ++nb) {
      const bf16x8 bk0 = *(const bf16x8*)&Ks[nb * 16 + lr][lg * 8];
      const bf16x8 bk1 = *(const bf16x8*)&Ks[nb * 16 + lr][32 + lg * 8];
      f32x4 a = (f32x4){0.f, 0.f, 0.f, 0.f};
      a = __builtin_amdgcn_mfma_f32_16x16x32_bf16(bk0, aq0, a, 0, 0, 0);
      a = __builtin_amdgcn_mfma_f32_16x16x32_bf16(bk1, aq1, a, 0, 0, 0);
      st[nb] = a;
    }

    // p = exp2(s') (log2e pre-folded into Q), partial denom, pack -> Ps
#pragma unroll
    for (int nb = 0; nb < 4; ++nb) {
      float p[4];
#pragma unroll
      for (int r = 0; r < 4; ++r) p[r] = exp2f(st[nb][r]);
      lsum += (p[0] + p[1]) + (p[2] + p[3]);
      uint2 u = pack4(p[0], p[1], p[2], p[3]);
      *reinterpret_cast<uint2*>(&Ps[w * 16 + lr][nb * 16 + lg * 4]) = u;
    }

    // O += P V  (Ps rows wave-private: same-wave DS in-order, no barrier)
    const bf16x8 pa0 = *(const bf16x8*)&Ps[w * 16 + lr][lg * 8];
    const bf16x8 pa1 = *(const bf16x8*)&Ps[w * 16 + lr][32 + lg * 8];
#pragma unroll
    for (int db = 0; db < 4; ++db) {
      const bf16x8 vb0 = *(const bf16x8*)&Vts[db * 16 + lr][lg * 8];
      const bf16x8 vb1 = *(const bf16x8*)&Vts[db * 16 + lr][32 + lg * 8];
      oacc[db] = __builtin_amdgcn_mfma_f32_16x16x32_bf16(pa0, vb0, oacc[db], 0, 0, 0);
      oacc[db] = __builtin_amdgcn_mfma_f32_16x16x32_bf16(pa1, vb1, oacc[db], 0, 0, 0);
    }

    // publish prefetched tile kt+1
    __syncthreads();
    *(u16x8*)&Ks[srow][scc * 8]       = kr0;
    *(u16x8*)&Ks[srow][scc * 8 + 32]  = kr1;
    *(u16x8*)&Vts[srow][scc * 8]      = vr0;
    *(u16x8*)&Vts[srow][scc * 8 + 32] = vr1;
    __syncthreads();
  }

  // tail tile (kt=12): kv 768..783 valid -> only nb=0, rows 0..15 of the tile
  {
    const bf16x8 bk0 = *(const bf16x8*)&Ks[lr][lg * 8];
    const bf16x8 bk1 = *(const bf16x8*)&Ks[lr][32 + lg * 8];
    f32x4 a = (f32x4){0.f, 0.f, 0.f, 0.f};
    a = __builtin_amdgcn_mfma_f32_16x16x32_bf16(bk0, aq0, a, 0, 0, 0);
    a = __builtin_amdgcn_mfma_f32_16x16x32_bf16(bk1, aq1, a, 0, 0, 0);
    float p[4];
#pragma unroll
    for (int r = 0; r < 4; ++r) p[r] = exp2f(a[r]);   // lg*4+r < 16: all valid
    lsum += (p[0] + p[1]) + (p[2] + p[3]);
    *reinterpret_cast<uint2*>(&Ps[w * 16 + lr][lg * 4]) = pack4(p[0], p[1], p[2], p[3]);
    uint2 z; z.x = 0u; z.y = 0u;
    *reinterpret_cast<uint2*>(&Ps[w * 16 + lr][16 + lg * 4]) = z;   // nb=1 slot = 0
    const bf16x8 pa0 = *(const bf16x8*)&Ps[w * 16 + lr][lg * 8];    // kv 0..31 local
#pragma unroll
    for (int db = 0; db < 4; ++db) {
      const bf16x8 vb0 = *(const bf16x8*)&Vts[db * 16 + lr][lg * 8];
      oacc[db] = __builtin_amdgcn_mfma_f32_16x16x32_bf16(pa0, vb0, oacc[db], 0, 0, 0);
    }
  }

  // final denominator: lanes {lr, lr+16, lr+32, lr+48} hold partials for q=lr
  float l = lsum;
  l += __shfl_xor(l, 16);
  l += __shfl_xor(l, 32);
  if (lg == 0) ls[w][lr] = l;
  const float4 lv = *(const float4*)&ls[w][lg * 4];   // wave-private, in-order

  const int b = bh / 3, h = bh - b * 3;
  float linv[4];
#pragma unroll
  for (int j = 0; j < 4; ++j) linv[j] = 1.f / ((&lv.x)[j]);
#pragma unroll
  for (int j = 0; j < 4; ++j) {
    const int qg = n0 + w * 16 + lg * 4 + j;   // oacc row = q
    unsigned short* orow = Ob + ((size_t)b * NQ + qg) * 192 + h * 64 + lr;
#pragma unroll
    for (int db = 0; db < 4; ++db) orow[db * 16] = f2b(oacc[db][j] * linv[j]);
  }
}

// ---------------------------------------------------------------------------
extern "C" void kernel_launch(void* const* d_in, const int* in_sizes, int n_in,
                              void* d_out, int out_size, void* d_ws, size_t ws_size,
                              hipStream_t stream)
{
  const float* x        = (const float*)d_in[0];
  const float* dw_q     = (const float*)d_in[1];
  const float* q_gamma  = (const float*)d_in[2];
  const float* q_beta   = (const float*)d_in[3];
  const float* q_mean   = (const float*)d_in[4];
  const float* q_var    = (const float*)d_in[5];
  const float* pw_q     = (const float*)d_in[6];
  const float* dw_kv    = (const float*)d_in[7];
  const float* kv_gamma = (const float*)d_in[8];
  const float* kv_beta  = (const float*)d_in[9];
  const float* kv_mean  = (const float*)d_in[10];
  const float* kv_var   = (const float*)d_in[11];
  const float* pw_kv    = (const float*)d_in[12];
  const float* out_w    = (const float*)d_in[13];
  const float* out_b    = (const float*)d_in[14];
  float* out = (float*)d_out;

  unsigned short* dwq   = (unsigned short*)d_ws;          // 25088*192 (later O)
  unsigned short* dwkv  = dwq   + (size_t)25088 * 192;    // 6272*192
  unsigned short* Qbuf  = dwkv  + (size_t)6272 * 192;     // 24*3136*64
  unsigned short* Kbuf  = Qbuf  + (size_t)24 * 3136 * 64; // 24*784*64
  unsigned short* Vtbuf = Kbuf  + (size_t)24 * 784 * 64;  // 24*64*784
  unsigned short* Wq    = Vtbuf + (size_t)24 * 784 * 64;  // 192*192
  unsigned short* Wkv   = Wq + 36864;                     // 384*192
  unsigned short* Wo    = Wkv + 73728;                    // 192*192

  // 1. fused: dwbn(q) + dwbn(kv) + weight prep
  stage1_kernel<<<6456, 256, 0, stream>>>(
      x, dw_q, q_gamma, q_beta, q_mean, q_var,
      dw_kv, kv_gamma, kv_beta, kv_mean, kv_var,
      pw_q, pw_kv, out_w, dwq, dwkv, Wq, Wkv, Wo);
  // 2. fused pointwise GEMMs: q -> Qbuf (scaled), kv -> Kbuf + Vtbuf
  gemm_qkv_kernel<<<882, 256, 0, stream>>>(dwq, dwkv, Wq, Wkv, Qbuf, Kbuf, Vtbuf);
  // 3. MFMA attention -> dwq (bf16 O, [25088][192]; dwq dead after step 2)
  attn_mfma_kernel<<<8 * 3 * 49, 256, 0, stream>>>(Qbuf, Kbuf, Vtbuf, dwq);
  // 4. output projection + bias -> d_out (fp32)
  gemm_out_kernel<<<588, 256, 0, stream>>>(dwq, Wo, out_b, out);
}